// Round 2
// baseline (533.580 us; speedup 1.0000x reference)
//
#include <hip/hip_runtime.h>
#include <cstdint>
#include <cmath>

#define BDIM 256

constexpr int Bsz = 32;
constexpr int Tt  = 512;
constexpr int Nn  = 1024;
constexpr float A_PLUS  = 0.005f;
constexpr float A_MINUS = 0.00525f;
constexpr float A_TP    = 0.0001f;
constexpr float A_TM    = 0.0001f;

typedef __attribute__((ext_vector_type(8))) short short8;   // 8 bf16 = 4 VGPRs
typedef __attribute__((ext_vector_type(4))) float float4v;  // MFMA acc

__device__ __forceinline__ unsigned short f2bf(float f) {
  // round-to-nearest-even fp32 -> bf16 (values are finite)
  unsigned u = __float_as_uint(f);
  u += 0x7fffu + ((u >> 16) & 1u);
  return (unsigned short)(u >> 16);
}

// ---------------------------------------------------------------------------
// Phase 1: trace recurrences -> bf16 operands in MFMA-tile-blocked layout.
// Operand matrices (rows = k = b*Tc + t_local, per chunk; 2 halves):
//   Abuf: rows [0,Kc) = P = A_PLUS*r1 + A_TP*r1*r2 (decayed), rows [Kc,2Kc) = pre
//   Bbuf: rows [0,Kc) = post,                    rows [Kc,2Kc) = -(A_MINUS*o1+A_TM*o1*o2)
// Blocked layout: tile = ((row>>5)*8 + (n>>7)); within tile, element (n,k-local j)
// lives at (n&127)*32 + ((j>>3) ^ ((n>>1)&3))*8 + (j&7)   [bank-conflict swizzle]
// ---------------------------------------------------------------------------
__global__ __launch_bounds__(BDIM) void trace_kernel(
    const float* __restrict__ pre, const float* __restrict__ post,
    unsigned short* __restrict__ Abuf, unsigned short* __restrict__ Bbuf,
    float* __restrict__ state, int t0, int Tc,
    float d_plus, float d_x, float d_minus, float d_y)
{
  int gid  = blockIdx.x * BDIM + threadIdx.x;   // [0, 2*B*N)
  int side = gid >= Bsz * Nn;                   // 0 = pre side, 1 = post side
  int id   = gid & (Bsz * Nn - 1);
  int b    = id >> 10;                          // / N
  int n    = id & (Nn - 1);

  const float* sp = (side ? post : pre) + ((size_t)b * Tt + t0) * Nn + n;
  float* st = state + 2 * ((size_t)side * Bsz * Nn + id);
  float tr1 = st[0], tr2 = st[1];

  float da = side ? d_minus : d_plus;
  float db = side ? d_y     : d_x;
  float c1 = side ? -A_MINUS : A_PLUS;
  float c2 = side ? -A_TM    : A_TP;
  unsigned short* dbuf = side ? Bbuf : Abuf;
  int Kc = Bsz * Tc;
  int ngrp = Tc >> 5;
  int sw = (n >> 1) & 3;                        // LDS bank swizzle for this row

  for (int g = 0; g < ngrp; ++g) {
    float s[32];
#pragma unroll
    for (int j = 0; j < 32; ++j) s[j] = sp[(size_t)(g * 32 + j) * Nn];

    short8 w0[4], w1[4];
#pragma unroll
    for (int j = 0; j < 32; ++j) {
      tr1 *= da; tr2 *= db;                       // decay first
      float tv = c1 * tr1 + c2 * (tr1 * tr2);     // trace factor (pre spike-add)
      unsigned short bs = f2bf(s[j]);
      unsigned short bt = f2bf(tv);
      unsigned short h0 = side ? bs : bt;         // half0: P (pre side) / post (post side)
      unsigned short h1 = side ? bt : bs;         // half1: pre / -Y
      w0[j >> 3][j & 7] = (short)h0;
      w1[j >> 3][j & 7] = (short)h1;
      tr1 += s[j]; tr2 += s[j];                   // then add spike
    }
    int kl = b * Tc + g * 32;                     // multiple of 32 -> full ktile row
    size_t d0 = ((size_t)((kl >> 5) * 8 + (n >> 7))) * 4096 + (size_t)(n & 127) * 32;
    size_t d1 = ((size_t)(((Kc + kl) >> 5) * 8 + (n >> 7))) * 4096 + (size_t)(n & 127) * 32;
#pragma unroll
    for (int i = 0; i < 4; ++i) {
      // swizzle = pure register permutation; addresses unchanged
      *(short8*)(dbuf + d0 + i * 8) = w0[i ^ sw];
      *(short8*)(dbuf + d1 + i * 8) = w1[i ^ sw];
    }
  }
  st[0] = tr1; st[1] = tr2;
}

// ---------------------------------------------------------------------------
// Phase 2: wu_partial[s] += A^T * B over this split's k-range.
// 128x128 tile / block, 4 waves, each wave 4x4 mfma_f32_16x16x32_bf16.
// Tiles are contiguous 8 KB blobs -> global_load_lds dwordx4 staging.
// LDS reads use the row-XOR swizzle baked into the global layout.
// ---------------------------------------------------------------------------
__global__ __launch_bounds__(BDIM) void gemm_kernel(
    const unsigned short* __restrict__ Abuf, const unsigned short* __restrict__ Bbuf,
    float* __restrict__ partials, int nkt)
{
  __shared__ unsigned short smem[8192];  // A tile [0,4096) elems, B tile [4096,8192)
  int tid = threadIdx.x;
  int pt = blockIdx.x & 7;
  int qt = blockIdx.x >> 3;
  int s  = blockIdx.y;

  float4v acc[4][4];
#pragma unroll
  for (int i = 0; i < 4; ++i)
#pragma unroll
    for (int j = 0; j < 4; ++j) acc[i][j] = (float4v){0.f, 0.f, 0.f, 0.f};

  int wid = tid >> 6, lane = tid & 63;
  int wr = wid >> 1, wc = wid & 1;
  int rA = wr * 64 + (lane & 15);
  int rB = wc * 64 + (lane & 15);
  // swizzled 16B-slot: lane gets k-group (lane>>4); stored slot is ^((row>>1)&3)
  int kg = (((lane >> 4) ^ ((lane >> 1) & 3)) * 8);

  const unsigned short* ga = Abuf + ((size_t)(s * nkt) * 8 + pt) * 4096 + tid * 8;
  const unsigned short* gb = Bbuf + ((size_t)(s * nkt) * 8 + qt) * 4096 + tid * 8;

  for (int kt = 0; kt < nkt; ++kt) {
    __builtin_amdgcn_global_load_lds(
        (const __attribute__((address_space(1))) unsigned int*)(ga),
        (__attribute__((address_space(3))) unsigned int*)(smem + tid * 8), 16, 0, 0);
    __builtin_amdgcn_global_load_lds(
        (const __attribute__((address_space(1))) unsigned int*)(ga + 2048),
        (__attribute__((address_space(3))) unsigned int*)(smem + 2048 + tid * 8), 16, 0, 0);
    __builtin_amdgcn_global_load_lds(
        (const __attribute__((address_space(1))) unsigned int*)(gb),
        (__attribute__((address_space(3))) unsigned int*)(smem + 4096 + tid * 8), 16, 0, 0);
    __builtin_amdgcn_global_load_lds(
        (const __attribute__((address_space(1))) unsigned int*)(gb + 2048),
        (__attribute__((address_space(3))) unsigned int*)(smem + 6144 + tid * 8), 16, 0, 0);
    ga += 8 * 4096; gb += 8 * 4096;
    __syncthreads();

    short8 af[4], bfv[4];
#pragma unroll
    for (int mi = 0; mi < 4; ++mi)
      af[mi] = *(const short8*)(smem + (rA + mi * 16) * 32 + kg);       // ds_read_b128
#pragma unroll
    for (int ni = 0; ni < 4; ++ni)
      bfv[ni] = *(const short8*)(smem + 4096 + (rB + ni * 16) * 32 + kg);
#pragma unroll
    for (int mi = 0; mi < 4; ++mi)
#pragma unroll
      for (int ni = 0; ni < 4; ++ni)
        acc[mi][ni] = __builtin_amdgcn_mfma_f32_16x16x32_bf16(af[mi], bfv[ni], acc[mi][ni], 0, 0, 0);
    __syncthreads();
  }

  // C/D layout: col = lane&15, row = (lane>>4)*4 + reg
  float* po = partials + (size_t)s * Nn * Nn;
#pragma unroll
  for (int mi = 0; mi < 4; ++mi) {
#pragma unroll
    for (int r = 0; r < 4; ++r) {
      int row = pt * 128 + wr * 64 + mi * 16 + (lane >> 4) * 4 + r;
#pragma unroll
      for (int ni = 0; ni < 4; ++ni) {
        int col = qt * 128 + wc * 64 + ni * 16 + (lane & 15);
        po[(size_t)row * Nn + col] += acc[mi][ni][r];   // accumulate across chunks
      }
    }
  }
}

// ---------------------------------------------------------------------------
// Phase 3: reduce split-K partials, apply 1/(B*T)
// ---------------------------------------------------------------------------
__global__ __launch_bounds__(BDIM) void reduce_kernel(
    const float* __restrict__ partials, float* __restrict__ out, int S, float scale)
{
  size_t i = (size_t)blockIdx.x * BDIM + threadIdx.x;
  float v = 0.f;
  for (int s = 0; s < S; ++s) v += partials[(size_t)s * (Nn * Nn) + i];
  out[i] = v * scale;
}

extern "C" void kernel_launch(void* const* d_in, const int* in_sizes, int n_in,
                              void* d_out, int out_size, void* d_ws, size_t ws_size,
                              hipStream_t stream)
{
  const float* pre  = (const float*)d_in[0];
  const float* post = (const float*)d_in[1];
  float* out = (float*)d_out;
  char* ws = (char*)d_ws;

  const int S = 8;
  size_t sz_part  = (size_t)S * Nn * Nn * 4;        // 32 MB split-K partials
  size_t sz_state = (size_t)2 * Bsz * Nn * 2 * 4;   // 512 KB trace state
  size_t fixed = sz_part + sz_state;

  // largest t-chunk that fits ws (deterministic: depends only on ws_size)
  int Tc = 32;
  for (int cand = 512; cand >= 32; cand >>= 1) {
    size_t need = fixed + 2ull * ((size_t)2 * Bsz * cand * Nn * 2);
    if (need <= ws_size) { Tc = cand; break; }
  }

  float* partials = (float*)ws;
  float* state    = (float*)(ws + sz_part);
  size_t sizeAB = (size_t)2 * Bsz * Tc * Nn * 2;    // one operand buffer, bytes
  unsigned short* Abuf = (unsigned short*)(ws + fixed);
  unsigned short* Bbuf = (unsigned short*)(ws + fixed + sizeAB);

  float d_plus  = expf(-1.0f / 20.0f);
  float d_x     = expf(-1.0f / 101.0f);
  float d_minus = expf(-1.0f / 20.0f);
  float d_y     = expf(-1.0f / 114.0f);

  hipMemsetAsync(partials, 0, sz_part, stream);
  hipMemsetAsync(state, 0, sz_state, stream);

  int C = Tt / Tc;
  int nkt_total = 2 * Tc;           // (2*B*Tc)/32 ktiles
  int nkt = nkt_total / S;

  for (int c = 0; c < C; ++c) {
    trace_kernel<<<2 * Bsz * Nn / BDIM, BDIM, 0, stream>>>(
        pre, post, Abuf, Bbuf, state, c * Tc, Tc, d_plus, d_x, d_minus, d_y);
    gemm_kernel<<<dim3(64, S), BDIM, 0, stream>>>(Abuf, Bbuf, partials, nkt);
  }
  reduce_kernel<<<(Nn * Nn) / BDIM, BDIM, 0, stream>>>(
      partials, out, S, 1.0f / (float)(Bsz * Tt));
}

// Round 3
// 284.621 us; speedup vs baseline: 1.8747x; 1.8747x over previous
//
#include <hip/hip_runtime.h>
#include <cstdint>
#include <cmath>

#define BDIM 256

constexpr int Bsz = 32;
constexpr int Tt  = 512;
constexpr int Nn  = 1024;
constexpr float A_PLUS  = 0.005f;
constexpr float A_MINUS = 0.00525f;
constexpr float A_TP    = 0.0001f;
constexpr float A_TM    = 0.0001f;

typedef __attribute__((ext_vector_type(8))) short short8;   // 8 bf16 = 4 VGPRs
typedef __attribute__((ext_vector_type(4))) float float4v;  // MFMA acc

__device__ __forceinline__ unsigned short f2bf(float f) {
  // round-to-nearest-even fp32 -> bf16 (values are finite)
  unsigned u = __float_as_uint(f);
  u += 0x7fffu + ((u >> 16) & 1u);
  return (unsigned short)(u >> 16);
}

// ---------------------------------------------------------------------------
// Phase 1: trace recurrences -> bf16 operands in MFMA-tile-blocked layout.
// Operand matrices (rows = k = b*Tc + t_local, per chunk; 2 halves):
//   Abuf: rows [0,Kc) = P = A_PLUS*r1 + A_TP*r1*r2 (decayed), rows [Kc,2Kc) = pre
//   Bbuf: rows [0,Kc) = post,                    rows [Kc,2Kc) = -(A_MINUS*o1+A_TM*o1*o2)
// Blocked layout: tile = ((row>>5)*8 + (n>>7)); within tile, element (n,k-local j)
// lives at (n&127)*32 + ((j>>3) ^ ((n>>1)&3))*8 + (j&7)   [bank-conflict swizzle,
// applied in the STORE ADDRESS — never as a dynamic register index]
// ---------------------------------------------------------------------------

#define LOAD_GRP(S_, G_) do {                                               \
    _Pragma("unroll")                                                       \
    for (int j = 0; j < 32; ++j)                                            \
      S_[j] = sp[(size_t)((G_) * 32 + j) * Nn];                             \
  } while (0)

#define PROC_GRP(S_, G_) do {                                               \
    short8 w0[4], w1[4];                                                    \
    _Pragma("unroll")                                                       \
    for (int j = 0; j < 32; ++j) {                                          \
      tr1 *= da; tr2 *= db;                       /* decay first */         \
      float tv = c1 * tr1 + c2 * (tr1 * tr2);     /* pre spike-add */       \
      unsigned short bs = f2bf(S_[j]);                                      \
      unsigned short bt = f2bf(tv);                                         \
      unsigned short h0 = side ? bs : bt;                                   \
      unsigned short h1 = side ? bt : bs;                                   \
      w0[j >> 3][j & 7] = (short)h0;                                        \
      w1[j >> 3][j & 7] = (short)h1;                                        \
      tr1 += S_[j]; tr2 += S_[j];                 /* then add spike */      \
    }                                                                       \
    int kl = b * Tc + (G_) * 32;                                            \
    size_t d0 = ((size_t)((kl >> 5) * 8 + (n >> 7))) * 4096                 \
              + (size_t)(n & 127) * 32;                                     \
    size_t d1 = ((size_t)(((Kc + kl) >> 5) * 8 + (n >> 7))) * 4096          \
              + (size_t)(n & 127) * 32;                                     \
    _Pragma("unroll")                                                       \
    for (int i = 0; i < 4; ++i) {                                           \
      *(short8*)(dbuf + d0 + ((i ^ sw) * 8)) = w0[i];                       \
      *(short8*)(dbuf + d1 + ((i ^ sw) * 8)) = w1[i];                       \
    }                                                                       \
  } while (0)

__global__ __launch_bounds__(BDIM) void trace_kernel(
    const float* __restrict__ pre, const float* __restrict__ post,
    unsigned short* __restrict__ Abuf, unsigned short* __restrict__ Bbuf,
    float* __restrict__ state, int t0, int Tc,
    float d_plus, float d_x, float d_minus, float d_y)
{
  int gid  = blockIdx.x * BDIM + threadIdx.x;   // [0, 2*B*N)
  int side = gid >= Bsz * Nn;                   // 0 = pre side, 1 = post side
  int id   = gid & (Bsz * Nn - 1);
  int b    = id >> 10;                          // / N
  int n    = id & (Nn - 1);

  const float* sp = (side ? post : pre) + ((size_t)b * Tt + t0) * Nn + n;
  float* st = state + 2 * ((size_t)side * Bsz * Nn + id);
  float tr1 = st[0], tr2 = st[1];

  float da = side ? d_minus : d_plus;
  float db = side ? d_y     : d_x;
  float c1 = side ? -A_MINUS : A_PLUS;
  float c2 = side ? -A_TM    : A_TP;
  unsigned short* dbuf = side ? Bbuf : Abuf;
  int Kc = Bsz * Tc;
  int ngrp = Tc >> 5;
  int sw = (n >> 1) & 3;                        // LDS bank swizzle for this row

  // software-pipelined group loop: prefetch g+1 while computing g
  float sA[32], sB[32];
  LOAD_GRP(sA, 0);
  int g = 0;
  while (true) {
    if (g + 1 < ngrp) LOAD_GRP(sB, g + 1);
    PROC_GRP(sA, g);
    ++g;
    if (g >= ngrp) break;
    if (g + 1 < ngrp) LOAD_GRP(sA, g + 1);
    PROC_GRP(sB, g);
    ++g;
    if (g >= ngrp) break;
  }

  st[0] = tr1; st[1] = tr2;
}

// ---------------------------------------------------------------------------
// Phase 2: wu_partial[s] = (or +=) A^T * B over this split's k-range.
// 128x128 tile / block, 4 waves, each wave 4x4 mfma_f32_16x16x32_bf16.
// Tiles are contiguous 8 KB blobs -> global_load_lds dwordx4 staging.
// LDS reads use the row-XOR swizzle baked into the global layout.
// ---------------------------------------------------------------------------
__global__ __launch_bounds__(BDIM) void gemm_kernel(
    const unsigned short* __restrict__ Abuf, const unsigned short* __restrict__ Bbuf,
    float* __restrict__ partials, int nkt, int first)
{
  __shared__ unsigned short smem[8192];  // A tile [0,4096) elems, B tile [4096,8192)
  int tid = threadIdx.x;
  int pt = blockIdx.x & 7;
  int qt = blockIdx.x >> 3;
  int s  = blockIdx.y;

  float4v acc[4][4];
#pragma unroll
  for (int i = 0; i < 4; ++i)
#pragma unroll
    for (int j = 0; j < 4; ++j) acc[i][j] = (float4v){0.f, 0.f, 0.f, 0.f};

  int wid = tid >> 6, lane = tid & 63;
  int wr = wid >> 1, wc = wid & 1;
  int rA = wr * 64 + (lane & 15);
  int rB = wc * 64 + (lane & 15);
  // swizzled 16B-slot: lane gets k-group (lane>>4); stored slot is ^((row>>1)&3)
  int kg = (((lane >> 4) ^ ((lane >> 1) & 3)) * 8);

  const unsigned short* ga = Abuf + ((size_t)(s * nkt) * 8 + pt) * 4096 + tid * 8;
  const unsigned short* gb = Bbuf + ((size_t)(s * nkt) * 8 + qt) * 4096 + tid * 8;

  for (int kt = 0; kt < nkt; ++kt) {
    __builtin_amdgcn_global_load_lds(
        (const __attribute__((address_space(1))) unsigned int*)(ga),
        (__attribute__((address_space(3))) unsigned int*)(smem + tid * 8), 16, 0, 0);
    __builtin_amdgcn_global_load_lds(
        (const __attribute__((address_space(1))) unsigned int*)(ga + 2048),
        (__attribute__((address_space(3))) unsigned int*)(smem + 2048 + tid * 8), 16, 0, 0);
    __builtin_amdgcn_global_load_lds(
        (const __attribute__((address_space(1))) unsigned int*)(gb),
        (__attribute__((address_space(3))) unsigned int*)(smem + 4096 + tid * 8), 16, 0, 0);
    __builtin_amdgcn_global_load_lds(
        (const __attribute__((address_space(1))) unsigned int*)(gb + 2048),
        (__attribute__((address_space(3))) unsigned int*)(smem + 6144 + tid * 8), 16, 0, 0);
    ga += 8 * 4096; gb += 8 * 4096;
    __syncthreads();

    short8 af[4], bfv[4];
#pragma unroll
    for (int mi = 0; mi < 4; ++mi)
      af[mi] = *(const short8*)(smem + (rA + mi * 16) * 32 + kg);       // ds_read_b128
#pragma unroll
    for (int ni = 0; ni < 4; ++ni)
      bfv[ni] = *(const short8*)(smem + 4096 + (rB + ni * 16) * 32 + kg);
#pragma unroll
    for (int mi = 0; mi < 4; ++mi)
#pragma unroll
      for (int ni = 0; ni < 4; ++ni)
        acc[mi][ni] = __builtin_amdgcn_mfma_f32_16x16x32_bf16(af[mi], bfv[ni], acc[mi][ni], 0, 0, 0);
    __syncthreads();
  }

  // C/D layout: col = lane&15, row = (lane>>4)*4 + reg
  float* po = partials + (size_t)s * Nn * Nn;
  if (first) {
#pragma unroll
    for (int mi = 0; mi < 4; ++mi)
#pragma unroll
      for (int r = 0; r < 4; ++r) {
        int row = pt * 128 + wr * 64 + mi * 16 + (lane >> 4) * 4 + r;
#pragma unroll
        for (int ni = 0; ni < 4; ++ni) {
          int col = qt * 128 + wc * 64 + ni * 16 + (lane & 15);
          po[(size_t)row * Nn + col] = acc[mi][ni][r];     // first chunk: plain store
        }
      }
  } else {
#pragma unroll
    for (int mi = 0; mi < 4; ++mi)
#pragma unroll
      for (int r = 0; r < 4; ++r) {
        int row = pt * 128 + wr * 64 + mi * 16 + (lane >> 4) * 4 + r;
#pragma unroll
        for (int ni = 0; ni < 4; ++ni) {
          int col = qt * 128 + wc * 64 + ni * 16 + (lane & 15);
          po[(size_t)row * Nn + col] += acc[mi][ni][r];    // later chunks accumulate
        }
      }
  }
}

// ---------------------------------------------------------------------------
// Phase 3: reduce split-K partials, apply 1/(B*T)
// ---------------------------------------------------------------------------
__global__ __launch_bounds__(BDIM) void reduce_kernel(
    const float* __restrict__ partials, float* __restrict__ out, int S, float scale)
{
  size_t i = (size_t)blockIdx.x * BDIM + threadIdx.x;
  float v = 0.f;
  for (int s = 0; s < S; ++s) v += partials[(size_t)s * (Nn * Nn) + i];
  out[i] = v * scale;
}

extern "C" void kernel_launch(void* const* d_in, const int* in_sizes, int n_in,
                              void* d_out, int out_size, void* d_ws, size_t ws_size,
                              hipStream_t stream)
{
  const float* pre  = (const float*)d_in[0];
  const float* post = (const float*)d_in[1];
  float* out = (float*)d_out;
  char* ws = (char*)d_ws;

  const int S = 8;
  size_t sz_part  = (size_t)S * Nn * Nn * 4;        // 32 MB split-K partials
  size_t sz_state = (size_t)2 * Bsz * Nn * 2 * 4;   // 512 KB trace state
  size_t fixed = sz_part + sz_state;

  // largest t-chunk that fits ws (deterministic: depends only on ws_size)
  int Tc = 32;
  for (int cand = 512; cand >= 32; cand >>= 1) {
    size_t need = fixed + 2ull * ((size_t)2 * Bsz * cand * Nn * 2);
    if (need <= ws_size) { Tc = cand; break; }
  }

  float* partials = (float*)ws;
  float* state    = (float*)(ws + sz_part);
  size_t sizeAB = (size_t)2 * Bsz * Tc * Nn * 2;    // one operand buffer, bytes
  unsigned short* Abuf = (unsigned short*)(ws + fixed);
  unsigned short* Bbuf = (unsigned short*)(ws + fixed + sizeAB);

  float d_plus  = expf(-1.0f / 20.0f);
  float d_x     = expf(-1.0f / 101.0f);
  float d_minus = expf(-1.0f / 20.0f);
  float d_y     = expf(-1.0f / 114.0f);

  int C = Tt / Tc;
  if (C > 1) hipMemsetAsync(partials, 0, sz_part, stream);  // C==1: gemm overwrites
  hipMemsetAsync(state, 0, sz_state, stream);

  int nkt_total = 2 * Tc;           // (2*B*Tc)/32 ktiles
  int nkt = nkt_total / S;

  for (int c = 0; c < C; ++c) {
    trace_kernel<<<2 * Bsz * Nn / BDIM, BDIM, 0, stream>>>(
        pre, post, Abuf, Bbuf, state, c * Tc, Tc, d_plus, d_x, d_minus, d_y);
    gemm_kernel<<<dim3(64, S), BDIM, 0, stream>>>(
        Abuf, Bbuf, partials, nkt, (C > 1) ? (c == 0) : 1);
  }
  reduce_kernel<<<(Nn * Nn) / BDIM, BDIM, 0, stream>>>(
      partials, out, S, 1.0f / (float)(Bsz * Tt));
}